// Round 1
// 2087.802 us; speedup vs baseline: 2.5632x; 2.5632x over previous
//
#include <hip/hip_runtime.h>

// Conv2d 3x3 SAME, stride 1, NCHW fp32.
// x: (16, 64, 256, 256), w: (128, 64, 3, 3), bias: (128,)
// out: (16, 128, 256, 256)
//
// V2: register-blocked direct conv.
//  - Block = 256 threads = 16 tx (x4 pixels) x 16 ty  -> 64(W) x 16(H) tile.
//  - 16 output channels per block (CB=16) -> input image fetched 8x total
//    (was 32x), FETCH_SIZE ~15.5 GB -> ~2.2 GB.
//  - Each thread: 6-wide input sliding window in registers; middle 4 taps are
//    one coalesced float4 load; only the +/-1 halo taps are guarded.
//  - Weights read with wave-uniform indices -> compiler emits s_load into
//    SGPRs; inner op is v_fmac_f32 acc, s_w, v_in (no LDS at all).
//  - acc[16][4] = 64 VGPR accumulators = 64 independent FMA chains (ILP).

#define H 256
#define W 256
#define CIN 64
#define COUT 128
#define NB 16
#define CB 16   // output channels per block
#define PW 4    // pixels per thread along W

__global__ __launch_bounds__(256) void Conv2dManual_77695958385099_kernel(
    const float* __restrict__ x, const float* __restrict__ w,
    const float* __restrict__ bias, float* __restrict__ out) {
    const int tx  = threadIdx.x & 15;
    const int ty  = threadIdx.x >> 4;
    const int ow0 = blockIdx.x * 64 + tx * 4;   // 16B-aligned
    const int oh  = blockIdx.y * 16 + ty;
    const int g   = blockIdx.z & 7;             // cout group (n-major z order
    const int n   = blockIdx.z >> 3;            //  -> concurrent g share image in L2)
    const int co  = g * CB;

    float acc[CB][PW];
#pragma unroll
    for (int c = 0; c < CB; ++c) {
        const float b = bias[co + c];           // uniform -> s_load
#pragma unroll
        for (int p = 0; p < PW; ++p) acc[c][p] = b;
    }

    const float* xn = x + (size_t)n * CIN * H * W;
    const float* wb = w + (size_t)co * CIN * 9;

    for (int ci = 0; ci < CIN; ++ci) {
        const float* xc = xn + (size_t)ci * H * W;

        // 3 rows x 6-wide sliding window, in registers.
        float in[3][6];
#pragma unroll
        for (int ky = 0; ky < 3; ++ky) {
            const int iy = oh + ky - 1;
            const bool yok = (unsigned)iy < (unsigned)H;
            if (yok) {
                const float* row = xc + iy * W;
                const float4 v = *(const float4*)(row + ow0);
                in[ky][1] = v.x; in[ky][2] = v.y;
                in[ky][3] = v.z; in[ky][4] = v.w;
                in[ky][0] = (ow0 > 0)      ? row[ow0 - 1]  : 0.0f;
                in[ky][5] = (ow0 < W - PW) ? row[ow0 + PW] : 0.0f;
            } else {
#pragma unroll
                for (int j = 0; j < 6; ++j) in[ky][j] = 0.0f;
            }
        }

        const float* wc = wb + ci * 9;
#pragma unroll
        for (int c = 0; c < CB; ++c) {
            const float* wcc = wc + (size_t)c * CIN * 9;
#pragma unroll
            for (int ky = 0; ky < 3; ++ky) {
#pragma unroll
                for (int kx = 0; kx < 3; ++kx) {
                    const float wv = wcc[ky * 3 + kx];  // uniform -> s_load
#pragma unroll
                    for (int p = 0; p < PW; ++p)
                        acc[c][p] += in[ky][kx + p] * wv;
                }
            }
        }
    }

    const size_t hw = (size_t)H * W;
    float* ob = out + ((size_t)n * COUT + co) * hw + (size_t)oh * W + ow0;
#pragma unroll
    for (int c = 0; c < CB; ++c) {
        float4 v;
        v.x = acc[c][0]; v.y = acc[c][1]; v.z = acc[c][2]; v.w = acc[c][3];
        *(float4*)(ob + (size_t)c * hw) = v;
    }
}

extern "C" void kernel_launch(void* const* d_in, const int* in_sizes, int n_in,
                              void* d_out, int out_size, void* d_ws, size_t ws_size,
                              hipStream_t stream) {
    const float* x = (const float*)d_in[0];
    const float* w = (const float*)d_in[1];
    const float* b = (const float*)d_in[2];
    float* out = (float*)d_out;

    dim3 grid(W / 64, H / 16, NB * (COUT / CB));  // (4, 16, 128)
    Conv2dManual_77695958385099_kernel<<<grid, 256, 0, stream>>>(x, w, b, out);
}

// Round 2
// 949.913 us; speedup vs baseline: 5.6335x; 2.1979x over previous
//
#include <hip/hip_runtime.h>

// Conv2d 3x3 SAME, stride 1: x (16,64,256,256) f32, w (128,64,3,3), bias (128) -> out (16,128,256,256)
//
// V3: fp16 MFMA implicit-GEMM (no fp32 MFMA exists on CDNA4; fp16 path = 2.5 PF vs 157 TF).
//  Pass 1a: w -> w_t[tap][s][cout][8ci] f16  (A-frag = per-lane b128, coalesced across lanes)
//  Pass 1b: x NCHW f32 -> NHWC f16 (row segment becomes contiguous; B-frag = ds_read_b128)
//  Conv: block = 128 cout x (2 rows x 64 cols). 4 waves (2 cout x 2 pix).
//        x tile [4 rows][66 cols][64 ci] f16 staged once in LDS, 16B-unit XOR swizzle
//        (byte ^= (s^(col&7))<<4) -> conflict-free ds_read_b128 B-frags.
//        Weights read per-tap straight from global (L2-resident) -> no barriers in tap loop.
//        mfma_f32_16x16x32_f16: A m=lane&15 (cout), B n=lane&15 (pixel), k=8*(lane>>4)+j
//        (consistent k-relabel for A and B), D row=(lane>>4)*4+r, col=lane&15.
// Accuracy: fp16 inputs, fp32 accum -> max err ~0.1 << 0.5 tol.

typedef _Float16 half8_t __attribute__((ext_vector_type(8)));
typedef _Float16 half4_t __attribute__((ext_vector_type(4)));
typedef float floatx4 __attribute__((ext_vector_type(4)));

#define HH 256
#define WW 256
#define CIN 64
#define COUT 128
#define NB 16

// ---------- pass 1a: weights OIHW f32 -> w_t[9][8][128][8] f16 ----------
__global__ void Conv2d_wprep_kernel(const float* __restrict__ w, _Float16* __restrict__ w_t) {
    int idx = blockIdx.x * 256 + threadIdx.x;
    if (idx >= 9 * 8 * 128 * 8) return;
    const int j = idx & 7, cout = (idx >> 3) & 127, s = (idx >> 10) & 7, t = idx >> 13;
    w_t[idx] = (_Float16)w[(cout * 64 + s * 8 + j) * 9 + t];
}

// ---------- pass 1b: x NCHW f32 -> NHWC f16 ----------
__global__ __launch_bounds__(256) void Conv2d_xprep_kernel(const float* __restrict__ x,
                                                           _Float16* __restrict__ x_h) {
    __shared__ _Float16 tile[64][68];   // pad 68 -> 8B-aligned half4 writes
    const int n = blockIdx.z, h = blockIdx.y, w0 = blockIdx.x * 64;
    const int tid = threadIdx.x;
    {
        const int c = tid >> 2, cb = (tid & 3) * 4;
        const float* src = x + ((size_t)(n * 64 + c) * 256 + h) * 256 + w0;
#pragma unroll
        for (int i = 0; i < 4; ++i) {
            const int col = cb + i * 16;
            const float4 v = *(const float4*)(src + col);
            half4_t hv;
            hv[0] = (_Float16)v.x; hv[1] = (_Float16)v.y;
            hv[2] = (_Float16)v.z; hv[3] = (_Float16)v.w;
            *(half4_t*)(&tile[c][col]) = hv;
        }
    }
    __syncthreads();
    {
        const int u = tid & 7, colg = tid >> 3;
#pragma unroll
        for (int b = 0; b < 2; ++b) {
            const int col = colg + 32 * b;
            half8_t vv;
#pragma unroll
            for (int j = 0; j < 8; ++j) vv[j] = tile[u * 8 + j][col];
            *(half8_t*)(x_h + ((size_t)((n * 256 + h) * 256) + w0 + col) * 64 + u * 8) = vv;
        }
    }
}

// ---------- conv: fp16 MFMA ----------
__global__ __launch_bounds__(256, 3) void Conv2dManual_77695958385099_kernel(
    const _Float16* __restrict__ x_h, const _Float16* __restrict__ w_t,
    const float* __restrict__ bias, float* __restrict__ out) {
    __shared__ __align__(16) unsigned char xs[4 * 66 * 128];  // 33792 B
    const int tid = threadIdx.x;
    const int l = tid & 63, wv = tid >> 6;
    const int wc = wv >> 1, wp = wv & 1;         // cout-half, pixel-half
    const int g = l >> 4, ln = l & 15;
    const int ow0 = blockIdx.x * 64, oh0 = blockIdx.y * 2, n = blockIdx.z;

    // ---- stage x tile: rows oh0-1..oh0+2, cols ow0-1..ow0+64, all 64 ci (f16) ----
    const int gstart = ow0 - 1;
    for (int u = tid; u < 4 * 528; u += 256) {    // 528 = 66 cols * 8 units/col
        const int row = u / 528, rem = u - row * 528;
        const int c = rem >> 3, s = rem & 7;
        const int gcol = gstart + c, ir = oh0 - 1 + row;
        int4 v = {0, 0, 0, 0};
        if ((unsigned)gcol < 256u && (unsigned)ir < 256u)
            v = *(const int4*)((const char*)x_h +
                               (size_t)((n * 256 + ir) * 256 + gcol) * 128 + s * 16);
        *(int4*)(xs + row * 8448 + c * 128 + ((s ^ (c & 7)) << 4)) = v;
    }
    __syncthreads();

    // ---- per-lane LDS byte offsets for B-frags: F[pf&1][kx][h] ----
    int F[2][3][2];
#pragma unroll
    for (int pfo = 0; pfo < 2; ++pfo)
#pragma unroll
        for (int kx = 0; kx < 3; ++kx)
#pragma unroll
            for (int h = 0; h < 2; ++h) {
                const int c = wp * 32 + pfo * 16 + kx + ln;
                const int s = 4 * h + g;
                F[pfo][kx][h] = c * 128 + ((s ^ (c & 7)) << 4);
            }

    const char* wlane = (const char*)w_t + g * 2048 + (wc * 64 + ln) * 16;

    floatx4 acc[4][4];
#pragma unroll
    for (int i = 0; i < 4; ++i)
#pragma unroll
        for (int j = 0; j < 4; ++j) acc[i][j] = (floatx4){0.f, 0.f, 0.f, 0.f};

    // ---- 9 taps x 2 K-steps, no barriers (LDS read-only, weights from L2) ----
#pragma unroll
    for (int ky = 0; ky < 3; ++ky)
#pragma unroll
        for (int kx = 0; kx < 3; ++kx) {
            const char* wt = wlane + (ky * 3 + kx) * 16384;
#pragma unroll
            for (int h = 0; h < 2; ++h) {
                const half8_t a0 = *(const half8_t*)(wt + h * 8192 + 0 * 256);
                const half8_t a1 = *(const half8_t*)(wt + h * 8192 + 1 * 256);
                const half8_t a2 = *(const half8_t*)(wt + h * 8192 + 2 * 256);
                const half8_t a3 = *(const half8_t*)(wt + h * 8192 + 3 * 256);
                const half8_t b0 = *(const half8_t*)(xs + F[0][kx][h] + (0 + ky) * 8448);
                const half8_t b1 = *(const half8_t*)(xs + F[1][kx][h] + (0 + ky) * 8448);
                const half8_t b2 = *(const half8_t*)(xs + F[0][kx][h] + (1 + ky) * 8448);
                const half8_t b3 = *(const half8_t*)(xs + F[1][kx][h] + (1 + ky) * 8448);
                acc[0][0] = __builtin_amdgcn_mfma_f32_16x16x32_f16(a0, b0, acc[0][0], 0, 0, 0);
                acc[0][1] = __builtin_amdgcn_mfma_f32_16x16x32_f16(a0, b1, acc[0][1], 0, 0, 0);
                acc[0][2] = __builtin_amdgcn_mfma_f32_16x16x32_f16(a0, b2, acc[0][2], 0, 0, 0);
                acc[0][3] = __builtin_amdgcn_mfma_f32_16x16x32_f16(a0, b3, acc[0][3], 0, 0, 0);
                acc[1][0] = __builtin_amdgcn_mfma_f32_16x16x32_f16(a1, b0, acc[1][0], 0, 0, 0);
                acc[1][1] = __builtin_amdgcn_mfma_f32_16x16x32_f16(a1, b1, acc[1][1], 0, 0, 0);
                acc[1][2] = __builtin_amdgcn_mfma_f32_16x16x32_f16(a1, b2, acc[1][2], 0, 0, 0);
                acc[1][3] = __builtin_amdgcn_mfma_f32_16x16x32_f16(a1, b3, acc[1][3], 0, 0, 0);
                acc[2][0] = __builtin_amdgcn_mfma_f32_16x16x32_f16(a2, b0, acc[2][0], 0, 0, 0);
                acc[2][1] = __builtin_amdgcn_mfma_f32_16x16x32_f16(a2, b1, acc[2][1], 0, 0, 0);
                acc[2][2] = __builtin_amdgcn_mfma_f32_16x16x32_f16(a2, b2, acc[2][2], 0, 0, 0);
                acc[2][3] = __builtin_amdgcn_mfma_f32_16x16x32_f16(a2, b3, acc[2][3], 0, 0, 0);
                acc[3][0] = __builtin_amdgcn_mfma_f32_16x16x32_f16(a3, b0, acc[3][0], 0, 0, 0);
                acc[3][1] = __builtin_amdgcn_mfma_f32_16x16x32_f16(a3, b1, acc[3][1], 0, 0, 0);
                acc[3][2] = __builtin_amdgcn_mfma_f32_16x16x32_f16(a3, b2, acc[3][2], 0, 0, 0);
                acc[3][3] = __builtin_amdgcn_mfma_f32_16x16x32_f16(a3, b3, acc[3][3], 0, 0, 0);
            }
        }

    // ---- epilogue: D row = g*4+r (cout), col = ln (pixel) ----
    float bv[4][4];
#pragma unroll
    for (int cf = 0; cf < 4; ++cf)
#pragma unroll
        for (int r = 0; r < 4; ++r) bv[cf][r] = bias[wc * 64 + cf * 16 + g * 4 + r];

    float* obase = out + ((size_t)(n * 128 + wc * 64 + g * 4) * 256 + oh0) * 256 +
                   ow0 + wp * 32 + ln;
#pragma unroll
    for (int cf = 0; cf < 4; ++cf)
#pragma unroll
        for (int pf = 0; pf < 4; ++pf)
#pragma unroll
            for (int r = 0; r < 4; ++r)
                obase[(size_t)(cf * 16 + r) * 65536 + (pf >> 1) * 256 + (pf & 1) * 16] =
                    acc[cf][pf][r] + bv[cf][r];
}

// ---------- fallback (proven V2 fp32) if workspace too small ----------
__global__ __launch_bounds__(256) void Conv2d_fallback_kernel(
    const float* __restrict__ x, const float* __restrict__ w,
    const float* __restrict__ bias, float* __restrict__ out) {
    const int tx = threadIdx.x & 15, ty = threadIdx.x >> 4;
    const int ow0 = blockIdx.x * 64 + tx * 4;
    const int oh = blockIdx.y * 16 + ty;
    const int gg = blockIdx.z & 7, n = blockIdx.z >> 3;
    const int co = gg * 16;
    float acc[16][4];
#pragma unroll
    for (int c = 0; c < 16; ++c) {
        const float b = bias[co + c];
#pragma unroll
        for (int p = 0; p < 4; ++p) acc[c][p] = b;
    }
    const float* xn = x + (size_t)n * CIN * HH * WW;
    const float* wb = w + (size_t)co * CIN * 9;
    for (int ci = 0; ci < CIN; ++ci) {
        const float* xc = xn + (size_t)ci * HH * WW;
        float in[3][6];
#pragma unroll
        for (int ky = 0; ky < 3; ++ky) {
            const int iy = oh + ky - 1;
            if ((unsigned)iy < (unsigned)HH) {
                const float* row = xc + iy * WW;
                const float4 v = *(const float4*)(row + ow0);
                in[ky][1] = v.x; in[ky][2] = v.y; in[ky][3] = v.z; in[ky][4] = v.w;
                in[ky][0] = (ow0 > 0) ? row[ow0 - 1] : 0.0f;
                in[ky][5] = (ow0 < WW - 4) ? row[ow0 + 4] : 0.0f;
            } else {
#pragma unroll
                for (int j = 0; j < 6; ++j) in[ky][j] = 0.0f;
            }
        }
        const float* wc2 = wb + ci * 9;
#pragma unroll
        for (int c = 0; c < 16; ++c) {
            const float* wcc = wc2 + (size_t)c * CIN * 9;
#pragma unroll
            for (int ky = 0; ky < 3; ++ky)
#pragma unroll
                for (int kx = 0; kx < 3; ++kx) {
                    const float wv2 = wcc[ky * 3 + kx];
#pragma unroll
                    for (int p = 0; p < 4; ++p) acc[c][p] += in[ky][kx + p] * wv2;
                }
        }
    }
    const size_t hw = (size_t)HH * WW;
    float* ob = out + ((size_t)n * COUT + co) * hw + (size_t)oh * WW + ow0;
#pragma unroll
    for (int c = 0; c < 16; ++c) {
        float4 v;
        v.x = acc[c][0]; v.y = acc[c][1]; v.z = acc[c][2]; v.w = acc[c][3];
        *(float4*)(ob + (size_t)c * hw) = v;
    }
}

extern "C" void kernel_launch(void* const* d_in, const int* in_sizes, int n_in,
                              void* d_out, int out_size, void* d_ws, size_t ws_size,
                              hipStream_t stream) {
    const float* x = (const float*)d_in[0];
    const float* w = (const float*)d_in[1];
    const float* b = (const float*)d_in[2];
    float* out = (float*)d_out;

    const size_t xh_bytes = (size_t)NB * 256 * 256 * 64 * 2;  // 128 MiB
    const size_t wt_bytes = (size_t)9 * 8 * 128 * 8 * 2;      // 144 KiB

    if (ws_size >= xh_bytes + wt_bytes) {
        char* ws = (char*)d_ws;
        _Float16* x_h = (_Float16*)ws;
        _Float16* w_t = (_Float16*)(ws + xh_bytes);
        Conv2d_wprep_kernel<<<dim3(288), 256, 0, stream>>>(w, w_t);
        Conv2d_xprep_kernel<<<dim3(4, 256, 16), 256, 0, stream>>>(x, x_h);
        Conv2dManual_77695958385099_kernel<<<dim3(4, 128, 16), 256, 0, stream>>>(
            x_h, w_t, b, out);
    } else {
        dim3 grid(WW / 64, HH / 16, NB * (COUT / 16));
        Conv2d_fallback_kernel<<<grid, 256, 0, stream>>>(x, w, b, out);
    }
}